// Round 5
// baseline (1386.625 us; speedup 1.0000x reference)
//
#include <hip/hip_runtime.h>
#include <cstdint>
#include <cstddef>

typedef unsigned short u16;
typedef unsigned int   u32;
typedef __bf16 bf16x8 __attribute__((ext_vector_type(8)));
typedef float  f32x4  __attribute__((ext_vector_type(4)));
typedef u32    u32x4  __attribute__((ext_vector_type(4)));

__device__ __forceinline__ float bf2f(u16 v) {
    union { u32 u; float f; } x; x.u = ((u32)v) << 16; return x.f;
}
__device__ __forceinline__ u16 f2bf(float f) {  // RNE, finite inputs
    u32 x = __float_as_uint(f);
    return (u16)((x + 0x7fffu + ((x >> 16) & 1u)) >> 16);
}

__device__ __forceinline__ void split8(const float4 a, const float4 b, u32x4& hi, u32x4& lo) {
    float x[8] = {a.x, a.y, a.z, a.w, b.x, b.y, b.z, b.w};
    u16 h[8], l[8];
#pragma unroll
    for (int i = 0; i < 8; i++) {
        h[i] = f2bf(x[i]);
        l[i] = f2bf(x[i] - bf2f(h[i]));   // x - bf16(x) is exact in fp32
    }
    hi = (u32x4){(u32)h[0] | ((u32)h[1] << 16), (u32)h[2] | ((u32)h[3] << 16),
                 (u32)h[4] | ((u32)h[5] << 16), (u32)h[6] | ((u32)h[7] << 16)};
    lo = (u32x4){(u32)l[0] | ((u32)l[1] << 16), (u32)l[2] | ((u32)l[3] << 16),
                 (u32)l[4] | ((u32)l[5] << 16), (u32)l[6] | ((u32)l[7] << 16)};
}
__device__ __forceinline__ void hi8(const float4 a, const float4 b, u32x4& hi) {
    float x[8] = {a.x, a.y, a.z, a.w, b.x, b.y, b.z, b.w};
    u16 h[8];
#pragma unroll
    for (int i = 0; i < 8; i++) h[i] = f2bf(x[i]);
    hi = (u32x4){(u32)h[0] | ((u32)h[1] << 16), (u32)h[2] | ((u32)h[3] << 16),
                 (u32)h[4] | ((u32)h[5] << 16), (u32)h[6] | ((u32)h[7] << 16)};
}

// ---------------- GEMM: C[m][n] = sum_k A[m][k]*B[n][k] + bias[n], fp32 in/out ----------------
// In-kernel bf16 hi/lo split; npass=3 => hi*hi + hi*lo + lo*hi (~fp32-accurate), npass=1 => hi*hi.
struct GemmArgs {
    const float* A0; const float* A1; const float* A2; const float* A3;  // fp32 sections, lda each
    const float* B;      // N x ldb fp32 (W row-major; C = A @ W^T)
    const float* bias;   // N fp32
    float* Z;            // M x N fp32 out
    int bk0, bk1, bk2, bk3;
    int nsec, SL, lda, ldb, N, relu, npass;
};

// tile 128(M) x 64(N), BK=32, 256 threads = 4 waves of 64x32
__global__ __launch_bounds__(256) void gemm_f32s(GemmArgs p) {
    __shared__ alignas(16) u16 Ah[128 * 32];
    __shared__ alignas(16) u16 Al[128 * 32];
    __shared__ alignas(16) u16 Bh[64 * 32];
    __shared__ alignas(16) u16 Bl[64 * 32];
    const int tid  = threadIdx.x;
    const int m0   = blockIdx.y * 128;
    const int n0   = blockIdx.x * 64;
    const int wave = tid >> 6, lane = tid & 63;
    const int quad = lane >> 4, lr = lane & 15;
    const int wm = (wave & 1) * 64, wn = (wave >> 1) * 32;
    const bool np3 = (p.npass == 3);

    f32x4 acc[4][2];
#pragma unroll
    for (int i = 0; i < 4; i++)
#pragma unroll
        for (int j = 0; j < 2; j++) acc[i][j] = (f32x4){0.f, 0.f, 0.f, 0.f};

    const int arow = tid >> 2;          // 0..63
    const int acol = (tid & 3) * 8;     // 0,8,16,24

    for (int s = 0; s < p.nsec; ++s) {
        const float* Ag = (s == 0) ? p.A0 : (s == 1) ? p.A1 : (s == 2) ? p.A2 : p.A3;
        const int    bo = (s == 0) ? p.bk0 : (s == 1) ? p.bk1 : (s == 2) ? p.bk2 : p.bk3;
        const float* ga0 = Ag + (size_t)(m0 + arow) * p.lda + acol;
        const float* ga1 = Ag + (size_t)(m0 + 64 + arow) * p.lda + acol;
        const float* gb0 = p.B + (size_t)(n0 + arow) * p.ldb + bo + acol;
        const int steps = p.SL >> 5;
        for (int t = 0; t < steps; ++t) {
            const float4 a0a = ((const float4*)ga0)[0], a0b = ((const float4*)ga0)[1];
            const float4 a1a = ((const float4*)ga1)[0], a1b = ((const float4*)ga1)[1];
            const float4 b0a = ((const float4*)gb0)[0], b0b = ((const float4*)gb0)[1];
            ga0 += 32; ga1 += 32; gb0 += 32;
            __syncthreads();   // previous iteration's LDS readers done
            if (np3) {
                u32x4 h, l;
                split8(a0a, a0b, h, l);
                *(u32x4*)&Ah[tid * 8] = h;        *(u32x4*)&Al[tid * 8] = l;
                split8(a1a, a1b, h, l);
                *(u32x4*)&Ah[2048 + tid * 8] = h; *(u32x4*)&Al[2048 + tid * 8] = l;
                split8(b0a, b0b, h, l);
                *(u32x4*)&Bh[tid * 8] = h;        *(u32x4*)&Bl[tid * 8] = l;
            } else {
                u32x4 h;
                hi8(a0a, a0b, h); *(u32x4*)&Ah[tid * 8] = h;
                hi8(a1a, a1b, h); *(u32x4*)&Ah[2048 + tid * 8] = h;
                hi8(b0a, b0b, h); *(u32x4*)&Bh[tid * 8] = h;
            }
            __syncthreads();
            bf16x8 ah[4], bh[2];
#pragma unroll
            for (int i = 0; i < 4; i++)
                ah[i] = *reinterpret_cast<const bf16x8*>(&Ah[(wm + i * 16 + lr) * 32 + quad * 8]);
#pragma unroll
            for (int j = 0; j < 2; j++)
                bh[j] = *reinterpret_cast<const bf16x8*>(&Bh[(wn + j * 16 + lr) * 32 + quad * 8]);
#pragma unroll
            for (int i = 0; i < 4; i++)
#pragma unroll
                for (int j = 0; j < 2; j++)
                    acc[i][j] = __builtin_amdgcn_mfma_f32_16x16x32_bf16(ah[i], bh[j], acc[i][j], 0, 0, 0);
            if (np3) {
                bf16x8 al[4], bl[2];
#pragma unroll
                for (int i = 0; i < 4; i++)
                    al[i] = *reinterpret_cast<const bf16x8*>(&Al[(wm + i * 16 + lr) * 32 + quad * 8]);
#pragma unroll
                for (int j = 0; j < 2; j++)
                    bl[j] = *reinterpret_cast<const bf16x8*>(&Bl[(wn + j * 16 + lr) * 32 + quad * 8]);
#pragma unroll
                for (int i = 0; i < 4; i++)
#pragma unroll
                    for (int j = 0; j < 2; j++) {
                        acc[i][j] = __builtin_amdgcn_mfma_f32_16x16x32_bf16(ah[i], bl[j], acc[i][j], 0, 0, 0);
                        acc[i][j] = __builtin_amdgcn_mfma_f32_16x16x32_bf16(al[i], bh[j], acc[i][j], 0, 0, 0);
                    }
            }
        }
    }

#pragma unroll
    for (int i = 0; i < 4; i++)
#pragma unroll
        for (int j = 0; j < 2; j++)
#pragma unroll
            for (int r = 0; r < 4; r++) {
                const int m = m0 + wm + i * 16 + quad * 4 + r;   // C/D row = quad*4+reg
                const int n = n0 + wn + j * 16 + lr;             // C/D col = lane&15
                float v = acc[i][j][r] + p.bias[n];
                if (p.relu) v = fmaxf(v, 0.f);
                p.Z[(size_t)m * p.N + n] = v;
            }
}

// ---------------- elementwise combines (4096x1024): fp32 out ----------------
__global__ __launch_bounds__(256) void combine1(const float* Z0, const float* Z1, const float* b1in,
                                                float* outr) {
    const int idx = blockIdx.x * 256 + threadIdx.x;
    const int m = idx >> 10;
    const float bf = b1in[2 * m];  // b1tm1f
    outr[idx] = bf * tanhf(Z1[idx]) + (1.f - bf) * tanhf(Z0[idx]);
}
__global__ __launch_bounds__(256) void combine2(const float* Z0, const float* Z1, const float* b2in,
                                                const float* rnn2in, const float* F1, float* outr) {
    const int idx = blockIdx.x * 256 + threadIdx.x;
    const int m = idx >> 10;
    const float b2f = b2in[2 * m];  // b2tm1f
    const float inner = (1.f - b2f) * tanhf(Z0[idx]) + b2f * tanhf(Z1[idx]);
    const float f1 = F1[m];
    outr[idx] = (1.f - f1) * rnn2in[idx] + f1 * inner;
}
__global__ __launch_bounds__(256) void combine3(const float* Z0, const float* Z1, const float* b3in,
                                                const float* rnn3in, const float* F1, const float* F2,
                                                float* outr) {
    const int idx = blockIdx.x * 256 + threadIdx.x;
    const int m = idx >> 10;
    const float b3f = b3in[2 * m];  // b3tm1f
    const float inner = b3f * tanhf(Z1[idx]) + (1.f - b3f) * tanhf(Z0[idx]);
    const float f1 = F1[m], f2 = F2[m];
    const float r3 = rnn3in[idx];
    outr[idx] = (1.f - f1) * r3 + f1 * ((1.f - f2) * r3 + f2 * inner);
}
__global__ __launch_bounds__(256) void combine4(const float* Z0, const float* rnn4in, const float* F1,
                                                const float* F2, const float* F3, float* outr) {
    const int idx = blockIdx.x * 256 + threadIdx.x;
    const int m = idx >> 10;
    const float f1 = F1[m], f2 = F2[m], f3 = F3[m];
    const float r4 = rnn4in[idx];
    const float t = tanhf(Z0[idx]);
    outr[idx] = (1.f - f1) * r4 + f1 * ((1.f - f2) * r4 + f2 * ((1.f - f3) * r4 + f3 * t));
}

// ---------------- Gumbel-hard decision GEMV (fp32): 1 wave per row ----------------
__global__ __launch_bounds__(256) void gemv_decide(const float* x, const float* W2, const float* bias2,
                                                   const float* gn, const float* bprev,
                                                   const float* Fp1, const float* Fp2,
                                                   float* bout, float* fout, int stage) {
    const int wave = threadIdx.x >> 6, lane = threadIdx.x & 63;
    const int m = blockIdx.x * 4 + wave;
    const float* row = x + (size_t)m * 1024;
    float s0 = 0.f, s1 = 0.f;
#pragma unroll 4
    for (int i = 0; i < 16; i++) {
        const int k = lane + 64 * i;
        const float v = row[k];
        s0 += v * W2[k];
        s1 += v * W2[1024 + k];
    }
    for (int off = 32; off > 0; off >>= 1) { s0 += __shfl_xor(s0, off); s1 += __shfl_xor(s1, off); }
    if (lane == 0) {
        const float l0 = s0 + bias2[0] + gn[2 * m];
        const float l1 = s1 + bias2[1] + gn[2 * m + 1];
        const float nf = (l0 >= l1) ? 1.f : 0.f;  // argmax picks index 0 on ties
        float v0, v1;
        if (stage == 1) {
            v0 = nf; v1 = 1.f - nf;
        } else if (stage == 2) {
            const float f1 = Fp1[m];
            const float p0 = bprev[2 * m], p1 = bprev[2 * m + 1];
            v0 = f1 * nf + (1.f - f1) * p0;
            v1 = f1 * (1.f - nf) + (1.f - f1) * p1;
        } else {
            const float f1 = Fp1[m], f2 = Fp2[m];
            const float p0 = bprev[2 * m], p1 = bprev[2 * m + 1];
            const float i0 = f2 * nf + (1.f - f2) * p0;
            const float i1 = f2 * (1.f - nf) + (1.f - f2) * p1;
            v0 = f1 * i0 + (1.f - f1) * p0;
            v1 = f1 * i1 + (1.f - f1) * p1;
        }
        fout[m] = v0;
        bout[2 * m] = v0; bout[2 * m + 1] = v1;
    }
}

// ---------------- g = sigmoid(W_g . hg + b): 1 wave per row, 4 outputs ----------------
__global__ __launch_bounds__(256) void gemv_g4(const float* hg, const float* Wg, const float* bg, float* G) {
    const int wave = threadIdx.x >> 6, lane = threadIdx.x & 63;
    const int m = blockIdx.x * 4 + wave;
    const float* row = hg + (size_t)m * 1024;
    float s[4] = {0.f, 0.f, 0.f, 0.f};
#pragma unroll 4
    for (int i = 0; i < 16; i++) {
        const int k = lane + 64 * i;
        const float v = row[k];
#pragma unroll
        for (int j = 0; j < 4; j++) s[j] += v * Wg[j * 1024 + k];
    }
    for (int off = 32; off > 0; off >>= 1)
#pragma unroll
        for (int j = 0; j < 4; j++) s[j] += __shfl_xor(s[j], off);
    if (lane == 0) {
#pragma unroll
        for (int j = 0; j < 4; j++) G[m * 4 + j] = 1.f / (1.f + expf(-(s[j] + bg[j])));
    }
}

// ---------------- gated strip: rows [row0, row0+2048) of concat_j g_j * rnn_jt (fp32) ----------------
__global__ __launch_bounds__(256) void gated_k(const float* rnnF, const float* G, float* gated, int row0) {
    const int idx = blockIdx.x * 256 + threadIdx.x;      // 0 .. 2048*4096
    const int m = row0 + (idx >> 12), rem = idx & 4095;
    const int j = rem >> 10, k = rem & 1023;
    gated[idx] = G[m * 4 + j] * rnnF[(size_t)j * 4194304 + (size_t)m * 1024 + k];
}

// ---------------- log_softmax over 256 cols: 1 wave per row, fp32 out ----------------
__global__ __launch_bounds__(256) void logsoftmax_k(const float* Z, float* out) {
    const int wave = threadIdx.x >> 6, lane = threadIdx.x & 63;
    const int row = blockIdx.x * 4 + wave;
    const size_t base = (size_t)row * 256;
    float x[4];
#pragma unroll
    for (int i = 0; i < 4; i++) x[i] = Z[base + lane + 64 * i];
    float mx = fmaxf(fmaxf(x[0], x[1]), fmaxf(x[2], x[3]));
    for (int off = 32; off > 0; off >>= 1) mx = fmaxf(mx, __shfl_xor(mx, off));
    float s = 0.f;
#pragma unroll
    for (int i = 0; i < 4; i++) s += expf(x[i] - mx);
    for (int off = 32; off > 0; off >>= 1) s += __shfl_xor(s, off);
    const float lse = mx + logf(s);
#pragma unroll
    for (int i = 0; i < 4; i++) out[base + lane + 64 * i] = x[i] - lse;
}

// ---------------- host ----------------
// d_out element offsets (return order: ctpi, b1t, b2t, b3t, rnn1t..rnn4t), ALL FP32
static const size_t OUT_B1 = 1048576, OUT_B2 = 1056768, OUT_B3 = 1064960;
static const size_t OUT_R1 = 1073152, OUT_R2 = 5267456, OUT_R3 = 9461760, OUT_R4 = 13656064;

extern "C" void kernel_launch(void* const* d_in, const int* in_sizes, int n_in,
                              void* d_out, int out_size, void* d_ws, size_t ws_size,
                              hipStream_t stream) {
    (void)in_sizes; (void)n_in; (void)out_size; (void)ws_size;
    // All tensors FP32 per the reference (R4 confirmed inputs fp32; R5 fixes outputs to fp32).
    const float* ct   = (const float*)d_in[0];
    const float* b1   = (const float*)d_in[1];
    const float* b2   = (const float*)d_in[2];
    const float* b3   = (const float*)d_in[3];
    const float* rnn1 = (const float*)d_in[4];
    const float* rnn2 = (const float*)d_in[5];
    const float* rnn3 = (const float*)d_in[6];
    const float* rnn4 = (const float*)d_in[7];
    const float* gn1  = (const float*)d_in[8];
    const float* gn2  = (const float*)d_in[9];
    const float* gn3  = (const float*)d_in[10];
    // d_in[11] = theta (int, ==1): argmax invariant to tau>0; hard one-hot forward cancels y
    const float* W_e    = (const float*)d_in[12]; const float* be    = (const float*)d_in[13];
    const float* W_r1b0 = (const float*)d_in[14]; const float* br1b0 = (const float*)d_in[15];
    const float* W_r1b1 = (const float*)d_in[16]; const float* br1b1 = (const float*)d_in[17];
    const float* W_b1   = (const float*)d_in[18]; const float* bb1   = (const float*)d_in[19];
    const float* W_r2b0 = (const float*)d_in[20]; const float* br2b0 = (const float*)d_in[21];
    const float* W_r2b1 = (const float*)d_in[22]; const float* br2b1 = (const float*)d_in[23];
    const float* W_b2   = (const float*)d_in[24]; const float* bb2   = (const float*)d_in[25];
    const float* W_r3b0 = (const float*)d_in[26]; const float* br3b0 = (const float*)d_in[27];
    const float* W_r3b1 = (const float*)d_in[28]; const float* br3b1 = (const float*)d_in[29];
    const float* W_b3   = (const float*)d_in[30]; const float* bb3   = (const float*)d_in[31];
    const float* W_r4   = (const float*)d_in[32]; const float* br4   = (const float*)d_in[33];
    const float* W_hg   = (const float*)d_in[34]; const float* bhg   = (const float*)d_in[35];
    const float* W_g    = (const float*)d_in[36]; const float* bg    = (const float*)d_in[37];
    const float* W_hct  = (const float*)d_in[38]; const float* bhct  = (const float*)d_in[39];
    const float* W_ct   = (const float*)d_in[40]; const float* bct   = (const float*)d_in[41];

    float* out = (float*)d_out;
    char* w = (char*)d_ws;
    const size_t MB = 1024 * 1024;
    // ws (48MB), lifetime-aliased:
    //  [ 0,16M): Z0 -> GATED[0,32M) -> ZC[0,4M)
    //  [16,32M): Z1 -> HGF -> (GATED tail)
    //  [32,48M): CTEF -> HCTF
    // rnn1t..rnn4t fp32 live directly in d_out (contiguous, stride 4194304 elems).
    // F1/F2/F3/G4 scalars live in the ctpi out-region (64KB; logsoftmax overwrites last).
    float* Z0   = (float*)(w + 0 * MB);
    float* Z1   = (float*)(w + 16 * MB);
    float* CTEF = (float*)(w + 32 * MB);
    float* HCTF = (float*)(w + 32 * MB);
    float* HGF  = (float*)(w + 16 * MB);
    float* GATED= (float*)(w + 0 * MB);
    float* ZC   = (float*)(w + 0 * MB);
    float* F1   = out;
    float* F2   = F1 + 4096;
    float* F3   = F1 + 8192;
    float* G4   = F1 + 12288;

    auto gemm = [&](const float* A0, const float* A1, const float* A2, const float* A3,
                    int bk1, int bk2, int bk3, int nsec, int SL, int lda,
                    const float* Bw, int ldb, const float* bias, int N,
                    int relu, int npass, float* Z, int Mblocks) {
        GemmArgs p;
        p.A0 = A0; p.A1 = A1; p.A2 = A2; p.A3 = A3;
        p.B = Bw; p.bias = bias; p.Z = Z;
        p.bk0 = 0; p.bk1 = bk1; p.bk2 = bk2; p.bk3 = bk3;
        p.nsec = nsec; p.SL = SL; p.lda = lda; p.ldb = ldb; p.N = N;
        p.relu = relu; p.npass = npass;
        dim3 grid(N / 64, Mblocks);
        gemm_f32s<<<grid, 256, 0, stream>>>(p);
    };
    const dim3 EW(16384), GV(1024);
    float* R1 = out + OUT_R1; float* R2 = out + OUT_R2;
    float* R3 = out + OUT_R3; float* R4 = out + OUT_R4;

    // 1) ct_e = relu(ct @ W_e^T + b) -> CTEF (3-pass: feeds decision chain)
    gemm(ct, 0, 0, 0, 0, 0, 0, 1, 256, 256, W_e, 256, be, 1024, 1, 3, CTEF, 32);
    // 2) rnn1 pre-activations (3-pass); combine -> rnn1t (d_out); decide b1
    gemm(rnn1, CTEF, 0, 0, 1024, 0, 0, 2, 1024, 1024, W_r1b0, 2048, br1b0, 1024, 0, 3, Z0, 32);
    gemm(rnn2, CTEF, 0, 0, 1024, 0, 0, 2, 1024, 1024, W_r1b1, 2048, br1b1, 1024, 0, 3, Z1, 32);
    combine1<<<EW, 256, 0, stream>>>(Z0, Z1, b1, R1);
    gemv_decide<<<GV, 256, 0, stream>>>(R1, W_b1, bb1, gn1, b1, F1, F1, out + OUT_B1, F1, 1);
    // 3) rnn2
    gemm(rnn2, R1, 0, 0, 1024, 0, 0, 2, 1024, 1024, W_r2b0, 2048, br2b0, 1024, 0, 3, Z0, 32);
    gemm(rnn3, R1, 0, 0, 1024, 0, 0, 2, 1024, 1024, W_r2b1, 2048, br2b1, 1024, 0, 3, Z1, 32);
    combine2<<<EW, 256, 0, stream>>>(Z0, Z1, b2, rnn2, F1, R2);
    gemv_decide<<<GV, 256, 0, stream>>>(R2, W_b2, bb2, gn2, b2, F1, F1, out + OUT_B2, F2, 2);
    // 4) rnn3
    gemm(rnn3, R2, 0, 0, 1024, 0, 0, 2, 1024, 1024, W_r3b0, 2048, br3b0, 1024, 0, 3, Z0, 32);
    gemm(rnn4, R2, 0, 0, 1024, 0, 0, 2, 1024, 1024, W_r3b1, 2048, br3b1, 1024, 0, 3, Z1, 32);
    combine3<<<EW, 256, 0, stream>>>(Z0, Z1, b3, rnn3, F1, F2, R3);
    gemv_decide<<<GV, 256, 0, stream>>>(R3, W_b3, bb3, gn3, b3, F1, F2, out + OUT_B3, F3, 3);
    // 5) rnn4 (tail: 1-pass)
    gemm(rnn4, R3, 0, 0, 1024, 0, 0, 2, 1024, 1024, W_r4, 2048, br4, 1024, 0, 1, Z0, 32);
    combine4<<<EW, 256, 0, stream>>>(Z0, rnn4, F1, F2, F3, R4);
    // 6) hg = relu(concat(rnn-t) @ W_hg^T) -> HGF; g
    gemm(R1, R2, R3, R4, 1024, 2048, 3072, 4, 1024, 1024, W_hg, 4096, bhg, 1024, 1, 1, HGF, 32);
    gemv_g4<<<GV, 256, 0, stream>>>(HGF, W_g, bg, G4);
    // 7) hctpi in two 2048-row strips: gated fp32 (32MB at ws[0,32M)) -> HCTF
    for (int strip = 0; strip < 2; ++strip) {
        gated_k<<<dim3(32768), 256, 0, stream>>>(R1, G4, GATED, strip * 2048);
        gemm(GATED, 0, 0, 0, 0, 0, 0, 1, 4096, 4096, W_hct, 4096, bhct, 1024, 1, 1,
             HCTF + (size_t)strip * 2097152, 16);
    }
    // 8) ctpi = log_softmax(hctpi @ W_ct^T + b)
    gemm(HCTF, 0, 0, 0, 0, 0, 0, 1, 1024, 1024, W_ct, 1024, bct, 256, 0, 1, ZC, 32);
    logsoftmax_k<<<GV, 256, 0, stream>>>(ZC, out);
}

// Round 6
// 1000.746 us; speedup vs baseline: 1.3856x; 1.3856x over previous
//
#include <hip/hip_runtime.h>
#include <cstdint>
#include <cstddef>

typedef unsigned short u16;
typedef __bf16 bf16x8 __attribute__((ext_vector_type(8)));
typedef float  f32x4  __attribute__((ext_vector_type(4)));

__device__ __forceinline__ void splitv(const float4 a, const float4 b, bf16x8& h, bf16x8& l) {
    float x[8] = {a.x, a.y, a.z, a.w, b.x, b.y, b.z, b.w};
#pragma unroll
    for (int i = 0; i < 8; i++) {
        __bf16 hh = (__bf16)x[i];
        h[i] = hh;
        l[i] = (__bf16)(x[i] - (float)hh);   // exact residual in fp32
    }
}
__device__ __forceinline__ void hiv(const float4 a, const float4 b, bf16x8& h) {
    float x[8] = {a.x, a.y, a.z, a.w, b.x, b.y, b.z, b.w};
#pragma unroll
    for (int i = 0; i < 8; i++) h[i] = (__bf16)x[i];
}

// ---- GEMM v2: dual-N fused, register-prefetch pipelined, XCD-slab swizzled ----
// C_half[m][n] = sum_k A_half[m][k] * B_half[n][k] + bias_half[n]
// npass=3: hi*hi + hi*lo + lo*hi (fp32-grade), npass=1: hi*hi (bf16-grade).
struct GemmArgs {
    const float* A0[4];      // half-0 A sections (row-major, lda)
    const float* A1[4];      // half-1 A sections
    const float* B0; const float* B1;       // N x ldb weights per half
    const float* bias0; const float* bias1; // N per half
    float* Z0; float* Z1;                   // M x N out per half
    int bk[4];               // per-section K offset into B
    int nsec, lda, ldb, N, spsl, relu, npass;  // spsl = log2(SL/32)
};

// tile 128(M) x 64(N), BK=32, 256 threads = 4 waves of 64x32; M fixed 4096 (32 mtiles).
// grid = NT_total*32 flat; swizzle: XCD k (bid%8) owns mtiles [4k,4k+4) for all ntiles.
__global__ __launch_bounds__(256, 4) void gemm_v2(GemmArgs p) {
    __shared__ u16 Ah[128 * 32];
    __shared__ u16 Al[128 * 32];
    __shared__ u16 Bh[64 * 32];
    __shared__ u16 Bl[64 * 32];
    const int tid = threadIdx.x;
    const int lin = blockIdx.x;
    const int mt = ((lin & 7) << 2) | ((lin >> 3) & 3);
    const int nt = lin >> 5;
    const int NTh = p.N >> 6;
    const int half = (nt >= NTh) ? 1 : 0;
    const int n0 = (nt - (half ? NTh : 0)) * 64;
    const int m0 = mt * 128;
    const float* Bw  = half ? p.B1 : p.B0;
    const float* bia = half ? p.bias1 : p.bias0;
    float* Z         = half ? p.Z1 : p.Z0;
    const float* const* Asec = half ? p.A1 : p.A0;

    const int wave = tid >> 6, lane = tid & 63;
    const int quad = lane >> 4, lr = lane & 15;
    const int wm = (wave & 1) * 64, wn = (wave >> 1) * 32;
    const bool np3 = (p.npass == 3);

    f32x4 acc[4][2];
#pragma unroll
    for (int i = 0; i < 4; i++)
#pragma unroll
        for (int j = 0; j < 2; j++) acc[i][j] = (f32x4){0.f, 0.f, 0.f, 0.f};

    const int arow = tid >> 2;          // 0..63
    const int acol = (tid & 3) * 8;     // 0,8,16,24
    const size_t rA0 = (size_t)(m0 + arow) * p.lda + acol;
    const size_t rA1 = rA0 + (size_t)64 * p.lda;
    const size_t rB  = (size_t)(n0 + arow) * p.ldb + acol;
    const int sps = 1 << p.spsl;
    const int total = p.nsec << p.spsl;

    float4 v0a, v0b, v1a, v1b, vba, vbb;
    {   // prefetch (s=0, t=0)
        const float* Ag = Asec[0];
        const float* a0 = Ag + rA0;
        const float* a1 = Ag + rA1;
        const float* b  = Bw + rB + p.bk[0];
        v0a = ((const float4*)a0)[0]; v0b = ((const float4*)a0)[1];
        v1a = ((const float4*)a1)[0]; v1b = ((const float4*)a1)[1];
        vba = ((const float4*)b)[0];  vbb = ((const float4*)b)[1];
    }

    for (int tt = 0; tt < total; ++tt) {
        __syncthreads();              // prior iter's LDS readers done
        bf16x8 h, l;
        if (np3) {
            splitv(v0a, v0b, h, l);
            *(bf16x8*)&Ah[tid * 8] = h;        *(bf16x8*)&Al[tid * 8] = l;
            splitv(v1a, v1b, h, l);
            *(bf16x8*)&Ah[2048 + tid * 8] = h; *(bf16x8*)&Al[2048 + tid * 8] = l;
            splitv(vba, vbb, h, l);
            *(bf16x8*)&Bh[tid * 8] = h;        *(bf16x8*)&Bl[tid * 8] = l;
        } else {
            hiv(v0a, v0b, h); *(bf16x8*)&Ah[tid * 8] = h;
            hiv(v1a, v1b, h); *(bf16x8*)&Ah[2048 + tid * 8] = h;
            hiv(vba, vbb, h); *(bf16x8*)&Bh[tid * 8] = h;
        }
        __syncthreads();              // tiles visible
        if (tt + 1 < total) {         // prefetch next K-step; waitcnt lands at next split
            const int ts = tt + 1;
            const int s = ts >> p.spsl, t = ts & (sps - 1);
            const float* Ag = Asec[s];
            const float* a0 = Ag + rA0 + t * 32;
            const float* a1 = Ag + rA1 + t * 32;
            const float* b  = Bw + rB + p.bk[s] + t * 32;
            v0a = ((const float4*)a0)[0]; v0b = ((const float4*)a0)[1];
            v1a = ((const float4*)a1)[0]; v1b = ((const float4*)a1)[1];
            vba = ((const float4*)b)[0];  vbb = ((const float4*)b)[1];
        }
        bf16x8 ah[4], bh2[2];
#pragma unroll
        for (int i = 0; i < 4; i++)
            ah[i] = *reinterpret_cast<const bf16x8*>(&Ah[(wm + i * 16 + lr) * 32 + quad * 8]);
#pragma unroll
        for (int j = 0; j < 2; j++)
            bh2[j] = *reinterpret_cast<const bf16x8*>(&Bh[(wn + j * 16 + lr) * 32 + quad * 8]);
#pragma unroll
        for (int i = 0; i < 4; i++)
#pragma unroll
            for (int j = 0; j < 2; j++)
                acc[i][j] = __builtin_amdgcn_mfma_f32_16x16x32_bf16(ah[i], bh2[j], acc[i][j], 0, 0, 0);
        if (np3) {
            bf16x8 al[4], bl2[2];
#pragma unroll
            for (int i = 0; i < 4; i++)
                al[i] = *reinterpret_cast<const bf16x8*>(&Al[(wm + i * 16 + lr) * 32 + quad * 8]);
#pragma unroll
            for (int j = 0; j < 2; j++)
                bl2[j] = *reinterpret_cast<const bf16x8*>(&Bl[(wn + j * 16 + lr) * 32 + quad * 8]);
#pragma unroll
            for (int i = 0; i < 4; i++)
#pragma unroll
                for (int j = 0; j < 2; j++) {
                    acc[i][j] = __builtin_amdgcn_mfma_f32_16x16x32_bf16(ah[i], bl2[j], acc[i][j], 0, 0, 0);
                    acc[i][j] = __builtin_amdgcn_mfma_f32_16x16x32_bf16(al[i], bh2[j], acc[i][j], 0, 0, 0);
                }
        }
    }

#pragma unroll
    for (int j = 0; j < 2; j++) {
        const int n = n0 + wn + j * 16 + lr;         // C/D col = lane&15
        const float bj = bia[n];
#pragma unroll
        for (int i = 0; i < 4; i++)
#pragma unroll
            for (int r = 0; r < 4; r++) {
                const int m = m0 + wm + i * 16 + quad * 4 + r;   // C/D row = quad*4+reg
                float v = acc[i][j][r] + bj;
                if (p.relu) v = fmaxf(v, 0.f);
                Z[(size_t)m * p.N + n] = v;
            }
    }
}

// ---------------- elementwise combines (4096x1024, float4/thread): fp32 out ----------------
__global__ __launch_bounds__(256) void combine1(const float* Z0, const float* Z1, const float* b1in,
                                                float* outr) {
    const int base = (blockIdx.x * 256 + threadIdx.x) * 4;
    const int m = base >> 10;
    const float bf = b1in[2 * m];
    const float4 z0 = *(const float4*)(Z0 + base), z1 = *(const float4*)(Z1 + base);
    float4 o;
    o.x = bf * tanhf(z1.x) + (1.f - bf) * tanhf(z0.x);
    o.y = bf * tanhf(z1.y) + (1.f - bf) * tanhf(z0.y);
    o.z = bf * tanhf(z1.z) + (1.f - bf) * tanhf(z0.z);
    o.w = bf * tanhf(z1.w) + (1.f - bf) * tanhf(z0.w);
    *(float4*)(outr + base) = o;
}
__global__ __launch_bounds__(256) void combine2(const float* Z0, const float* Z1, const float* b2in,
                                                const float* rnn2in, const float* F1, float* outr) {
    const int base = (blockIdx.x * 256 + threadIdx.x) * 4;
    const int m = base >> 10;
    const float b2f = b2in[2 * m], f1 = F1[m];
    const float4 z0 = *(const float4*)(Z0 + base), z1 = *(const float4*)(Z1 + base);
    const float4 r2 = *(const float4*)(rnn2in + base);
    float4 o;
    o.x = (1.f - f1) * r2.x + f1 * ((1.f - b2f) * tanhf(z0.x) + b2f * tanhf(z1.x));
    o.y = (1.f - f1) * r2.y + f1 * ((1.f - b2f) * tanhf(z0.y) + b2f * tanhf(z1.y));
    o.z = (1.f - f1) * r2.z + f1 * ((1.f - b2f) * tanhf(z0.z) + b2f * tanhf(z1.z));
    o.w = (1.f - f1) * r2.w + f1 * ((1.f - b2f) * tanhf(z0.w) + b2f * tanhf(z1.w));
    *(float4*)(outr + base) = o;
}
__global__ __launch_bounds__(256) void combine3(const float* Z0, const float* Z1, const float* b3in,
                                                const float* rnn3in, const float* F1, const float* F2,
                                                float* outr) {
    const int base = (blockIdx.x * 256 + threadIdx.x) * 4;
    const int m = base >> 10;
    const float b3f = b3in[2 * m], f1 = F1[m], f2 = F2[m];
    const float4 z0 = *(const float4*)(Z0 + base), z1 = *(const float4*)(Z1 + base);
    const float4 r3 = *(const float4*)(rnn3in + base);
    float4 o;
    o.x = (1.f - f1) * r3.x + f1 * ((1.f - f2) * r3.x + f2 * (b3f * tanhf(z1.x) + (1.f - b3f) * tanhf(z0.x)));
    o.y = (1.f - f1) * r3.y + f1 * ((1.f - f2) * r3.y + f2 * (b3f * tanhf(z1.y) + (1.f - b3f) * tanhf(z0.y)));
    o.z = (1.f - f1) * r3.z + f1 * ((1.f - f2) * r3.z + f2 * (b3f * tanhf(z1.z) + (1.f - b3f) * tanhf(z0.z)));
    o.w = (1.f - f1) * r3.w + f1 * ((1.f - f2) * r3.w + f2 * (b3f * tanhf(z1.w) + (1.f - b3f) * tanhf(z0.w)));
    *(float4*)(outr + base) = o;
}
__global__ __launch_bounds__(256) void combine4(const float* Z0, const float* rnn4in, const float* F1,
                                                const float* F2, const float* F3, float* outr) {
    const int base = (blockIdx.x * 256 + threadIdx.x) * 4;
    const int m = base >> 10;
    const float f1 = F1[m], f2 = F2[m], f3 = F3[m];
    const float4 z0 = *(const float4*)(Z0 + base);
    const float4 r4 = *(const float4*)(rnn4in + base);
    float4 o;
    o.x = (1.f - f1) * r4.x + f1 * ((1.f - f2) * r4.x + f2 * ((1.f - f3) * r4.x + f3 * tanhf(z0.x)));
    o.y = (1.f - f1) * r4.y + f1 * ((1.f - f2) * r4.y + f2 * ((1.f - f3) * r4.y + f3 * tanhf(z0.y)));
    o.z = (1.f - f1) * r4.z + f1 * ((1.f - f2) * r4.z + f2 * ((1.f - f3) * r4.z + f3 * tanhf(z0.z)));
    o.w = (1.f - f1) * r4.w + f1 * ((1.f - f2) * r4.w + f2 * ((1.f - f3) * r4.w + f3 * tanhf(z0.w)));
    *(float4*)(outr + base) = o;
}

// ---------------- Gumbel-hard decision GEMV (fp32): 1 wave per row ----------------
__global__ __launch_bounds__(256) void gemv_decide(const float* x, const float* W2, const float* bias2,
                                                   const float* gn, const float* bprev,
                                                   const float* Fp1, const float* Fp2,
                                                   float* bout, float* fout, int stage) {
    const int wave = threadIdx.x >> 6, lane = threadIdx.x & 63;
    const int m = blockIdx.x * 4 + wave;
    const float* row = x + (size_t)m * 1024;
    float s0 = 0.f, s1 = 0.f;
#pragma unroll 4
    for (int i = 0; i < 16; i++) {
        const int k = lane + 64 * i;
        const float v = row[k];
        s0 += v * W2[k];
        s1 += v * W2[1024 + k];
    }
    for (int off = 32; off > 0; off >>= 1) { s0 += __shfl_xor(s0, off); s1 += __shfl_xor(s1, off); }
    if (lane == 0) {
        const float l0 = s0 + bias2[0] + gn[2 * m];
        const float l1 = s1 + bias2[1] + gn[2 * m + 1];
        const float nf = (l0 >= l1) ? 1.f : 0.f;
        float v0, v1;
        if (stage == 1) {
            v0 = nf; v1 = 1.f - nf;
        } else if (stage == 2) {
            const float f1 = Fp1[m];
            const float p0 = bprev[2 * m], p1 = bprev[2 * m + 1];
            v0 = f1 * nf + (1.f - f1) * p0;
            v1 = f1 * (1.f - nf) + (1.f - f1) * p1;
        } else {
            const float f1 = Fp1[m], f2 = Fp2[m];
            const float p0 = bprev[2 * m], p1 = bprev[2 * m + 1];
            const float i0 = f2 * nf + (1.f - f2) * p0;
            const float i1 = f2 * (1.f - nf) + (1.f - f2) * p1;
            v0 = f1 * i0 + (1.f - f1) * p0;
            v1 = f1 * i1 + (1.f - f1) * p1;
        }
        fout[m] = v0;
        bout[2 * m] = v0; bout[2 * m + 1] = v1;
    }
}

// ---------------- g = sigmoid(W_g . hg + b): 1 wave per row, 4 outputs ----------------
__global__ __launch_bounds__(256) void gemv_g4(const float* hg, const float* Wg, const float* bg, float* G) {
    const int wave = threadIdx.x >> 6, lane = threadIdx.x & 63;
    const int m = blockIdx.x * 4 + wave;
    const float* row = hg + (size_t)m * 1024;
    float s[4] = {0.f, 0.f, 0.f, 0.f};
#pragma unroll 4
    for (int i = 0; i < 16; i++) {
        const int k = lane + 64 * i;
        const float v = row[k];
#pragma unroll
        for (int j = 0; j < 4; j++) s[j] += v * Wg[j * 1024 + k];
    }
    for (int off = 32; off > 0; off >>= 1)
#pragma unroll
        for (int j = 0; j < 4; j++) s[j] += __shfl_xor(s[j], off);
    if (lane == 0) {
#pragma unroll
        for (int j = 0; j < 4; j++) G[m * 4 + j] = 1.f / (1.f + expf(-(s[j] + bg[j])));
    }
}

// ---------------- gated = concat_j g_j * rnn_jt (4096 x 4096 fp32, float4/thread) ----------------
__global__ __launch_bounds__(256) void gated_k(const float* rnnF, const float* G, float* gated) {
    const int base = (blockIdx.x * 256 + threadIdx.x) * 4;
    const int m = base >> 12, rem = base & 4095;
    const int j = rem >> 10, k = rem & 1023;
    const float g = G[m * 4 + j];
    const float4 r = *(const float4*)(rnnF + (size_t)j * 4194304 + (size_t)m * 1024 + k);
    float4 o; o.x = g * r.x; o.y = g * r.y; o.z = g * r.z; o.w = g * r.w;
    *(float4*)(gated + base) = o;
}

// ---------------- log_softmax over 256 cols: 1 wave per row, fp32 out ----------------
__global__ __launch_bounds__(256) void logsoftmax_k(const float* Z, float* out) {
    const int wave = threadIdx.x >> 6, lane = threadIdx.x & 63;
    const int row = blockIdx.x * 4 + wave;
    const size_t base = (size_t)row * 256;
    float x[4];
#pragma unroll
    for (int i = 0; i < 4; i++) x[i] = Z[base + lane + 64 * i];
    float mx = fmaxf(fmaxf(x[0], x[1]), fmaxf(x[2], x[3]));
    for (int off = 32; off > 0; off >>= 1) mx = fmaxf(mx, __shfl_xor(mx, off));
    float s = 0.f;
#pragma unroll
    for (int i = 0; i < 4; i++) s += expf(x[i] - mx);
    for (int off = 32; off > 0; off >>= 1) s += __shfl_xor(s, off);
    const float lse = mx + logf(s);
#pragma unroll
    for (int i = 0; i < 4; i++) out[base + lane + 64 * i] = x[i] - lse;
}

// ---------------- host ----------------
static const size_t OUT_B1 = 1048576, OUT_B2 = 1056768, OUT_B3 = 1064960;
static const size_t OUT_R1 = 1073152, OUT_R2 = 5267456, OUT_R3 = 9461760, OUT_R4 = 13656064;

extern "C" void kernel_launch(void* const* d_in, const int* in_sizes, int n_in,
                              void* d_out, int out_size, void* d_ws, size_t ws_size,
                              hipStream_t stream) {
    (void)in_sizes; (void)n_in; (void)out_size; (void)ws_size;
    const float* ct   = (const float*)d_in[0];
    const float* b1   = (const float*)d_in[1];
    const float* b2   = (const float*)d_in[2];
    const float* b3   = (const float*)d_in[3];
    const float* rnn1 = (const float*)d_in[4];
    const float* rnn2 = (const float*)d_in[5];
    const float* rnn3 = (const float*)d_in[6];
    const float* rnn4 = (const float*)d_in[7];
    const float* gn1  = (const float*)d_in[8];
    const float* gn2  = (const float*)d_in[9];
    const float* gn3  = (const float*)d_in[10];
    const float* W_e    = (const float*)d_in[12]; const float* be    = (const float*)d_in[13];
    const float* W_r1b0 = (const float*)d_in[14]; const float* br1b0 = (const float*)d_in[15];
    const float* W_r1b1 = (const float*)d_in[16]; const float* br1b1 = (const float*)d_in[17];
    const float* W_b1   = (const float*)d_in[18]; const float* bb1   = (const float*)d_in[19];
    const float* W_r2b0 = (const float*)d_in[20]; const float* br2b0 = (const float*)d_in[21];
    const float* W_r2b1 = (const float*)d_in[22]; const float* br2b1 = (const float*)d_in[23];
    const float* W_b2   = (const float*)d_in[24]; const float* bb2   = (const float*)d_in[25];
    const float* W_r3b0 = (const float*)d_in[26]; const float* br3b0 = (const float*)d_in[27];
    const float* W_r3b1 = (const float*)d_in[28]; const float* br3b1 = (const float*)d_in[29];
    const float* W_b3   = (const float*)d_in[30]; const float* bb3   = (const float*)d_in[31];
    const float* W_r4   = (const float*)d_in[32]; const float* br4   = (const float*)d_in[33];
    const float* W_hg   = (const float*)d_in[34]; const float* bhg   = (const float*)d_in[35];
    const float* W_g    = (const float*)d_in[36]; const float* bg    = (const float*)d_in[37];
    const float* W_hct  = (const float*)d_in[38]; const float* bhct  = (const float*)d_in[39];
    const float* W_ct   = (const float*)d_in[40]; const float* bct   = (const float*)d_in[41];

    float* out = (float*)d_out;
    char* w = (char*)d_ws;
    const size_t MB = 1024 * 1024;
    // ws (80MB): Z0[0,16) Z1[16,32) CTEF[32,48) HGF[48,64) | GATED[0,64) | HCTF[64,80) | ZC[0,4)
    float* Z0    = (float*)(w + 0 * MB);
    float* Z1    = (float*)(w + 16 * MB);
    float* CTEF  = (float*)(w + 32 * MB);
    float* HGF   = (float*)(w + 48 * MB);
    float* GATED = (float*)(w + 0 * MB);
    float* HCTF  = (float*)(w + 64 * MB);
    float* ZC    = (float*)(w + 0 * MB);
    float* F1 = out; float* F2 = F1 + 4096; float* F3 = F1 + 8192; float* G4 = F1 + 12288;
    float* R1 = out + OUT_R1; float* R2 = out + OUT_R2;
    float* R3 = out + OUT_R3; float* R4 = out + OUT_R4;

    auto gemm = [&](const float* a00, const float* a01, const float* a02, const float* a03,
                    const float* a10, const float* a11,
                    const float* B0w, const float* B1w, const float* bi0, const float* bi1,
                    float* z0, float* z1, int bk1, int bk2, int bk3,
                    int nsec, int lda, int ldb, int N, int spsl, int relu, int npass, int NT) {
        GemmArgs p;
        p.A0[0] = a00; p.A0[1] = a01; p.A0[2] = a02; p.A0[3] = a03;
        p.A1[0] = a10 ? a10 : a00; p.A1[1] = a11 ? a11 : a01; p.A1[2] = a02; p.A1[3] = a03;
        p.B0 = B0w; p.B1 = B1w; p.bias0 = bi0; p.bias1 = bi1; p.Z0 = z0; p.Z1 = z1;
        p.bk[0] = 0; p.bk[1] = bk1; p.bk[2] = bk2; p.bk[3] = bk3;
        p.nsec = nsec; p.lda = lda; p.ldb = ldb; p.N = N; p.spsl = spsl;
        p.relu = relu; p.npass = npass;
        gemm_v2<<<dim3(NT * 32), 256, 0, stream>>>(p);
    };
    const dim3 EW(4096), GV(1024);

    // 1) ct_e = relu(ct @ W_e^T + b) -> CTEF (3-pass)
    gemm(ct, 0, 0, 0, 0, 0, W_e, W_e, be, be, CTEF, CTEF,
         0, 0, 0, 1, 256, 256, 1024, 3, 1, 3, 16);
    // 2) rnn1 dual: Z0=[rnn1,CTE]@Wb0^T, Z1=[rnn2,CTE]@Wb1^T (3-pass)
    gemm(rnn1, CTEF, 0, 0, rnn2, CTEF, W_r1b0, W_r1b1, br1b0, br1b1, Z0, Z1,
         1024, 0, 0, 2, 1024, 2048, 1024, 5, 0, 3, 32);
    combine1<<<EW, 256, 0, stream>>>(Z0, Z1, b1, R1);
    gemv_decide<<<GV, 256, 0, stream>>>(R1, W_b1, bb1, gn1, b1, F1, F1, out + OUT_B1, F1, 1);
    // 3) rnn2 dual
    gemm(rnn2, R1, 0, 0, rnn3, R1, W_r2b0, W_r2b1, br2b0, br2b1, Z0, Z1,
         1024, 0, 0, 2, 1024, 2048, 1024, 5, 0, 3, 32);
    combine2<<<EW, 256, 0, stream>>>(Z0, Z1, b2, rnn2, F1, R2);
    gemv_decide<<<GV, 256, 0, stream>>>(R2, W_b2, bb2, gn2, b2, F1, F1, out + OUT_B2, F2, 2);
    // 4) rnn3 dual
    gemm(rnn3, R2, 0, 0, rnn4, R2, W_r3b0, W_r3b1, br3b0, br3b1, Z0, Z1,
         1024, 0, 0, 2, 1024, 2048, 1024, 5, 0, 3, 32);
    combine3<<<EW, 256, 0, stream>>>(Z0, Z1, b3, rnn3, F1, F2, R3);
    gemv_decide<<<GV, 256, 0, stream>>>(R3, W_b3, bb3, gn3, b3, F1, F2, out + OUT_B3, F3, 3);
    // 5) rnn4 (1-pass)
    gemm(rnn4, R3, 0, 0, 0, 0, W_r4, W_r4, br4, br4, Z0, Z0,
         1024, 0, 0, 2, 1024, 2048, 1024, 5, 0, 1, 16);
    combine4<<<EW, 256, 0, stream>>>(Z0, rnn4, F1, F2, F3, R4);
    // 6) hg = relu(concat(R1..R4) @ W_hg^T) -> HGF (1-pass); g
    gemm(R1, R2, R3, R4, 0, 0, W_hg, W_hg, bhg, bhg, HGF, HGF,
         1024, 2048, 3072, 4, 1024, 4096, 1024, 5, 1, 1, 16);
    gemv_g4<<<GV, 256, 0, stream>>>(HGF, W_g, bg, G4);
    // 7) gated (64MB at ws[0,64)); hctpi (1-pass)
    gated_k<<<dim3(16384), 256, 0, stream>>>(R1, G4, GATED);
    gemm(GATED, 0, 0, 0, 0, 0, W_hct, W_hct, bhct, bhct, HCTF, HCTF,
         0, 0, 0, 1, 4096, 4096, 1024, 7, 1, 1, 16);
    // 8) ctpi = log_softmax(hctpi @ W_ct^T + b)
    gemm(HCTF, 0, 0, 0, 0, 0, W_ct, W_ct, bct, bct, ZC, ZC,
         0, 0, 0, 1, 1024, 1024, 256, 5, 0, 1, 4);
    logsoftmax_k<<<GV, 256, 0, stream>>>(ZC, out);
}